// Round 1
// baseline (6086.052 us; speedup 1.0000x reference)
//
#include <hip/hip_runtime.h>

#define S_LEN 2048
#define BATCH 4
#define DMODEL 512
#define NHEADS 4
#define DHEAD 128
#define PRE 20

// ---------------- embedding + positional encoding ----------------
__global__ __launch_bounds__(256) void embed_kernel(
    const float* __restrict__ src, const float* __restrict__ ew,
    const float* __restrict__ eb, float* __restrict__ X)
{
    int rid = blockIdx.x;              // b*S + s
    int s = rid & (S_LEN - 1);
    int tid = threadIdx.x;
    __shared__ float sr[25];
    if (tid < 25) sr[tid] = src[rid * 25 + tid];
    __syncthreads();
    #pragma unroll
    for (int rep = 0; rep < 2; rep++) {
        int d = tid + rep * 256;
        float a = eb[d];
        #pragma unroll
        for (int k = 0; k < 25; k++) a = fmaf(sr[k], ew[d * 25 + k], a);
        int i2 = d & ~1;
        float div = expf(-(float)i2 * (9.210340371976184f / 512.f)); // ln(10000)/512
        float ang = (float)s * div;
        a += (d & 1) ? cosf(ang) : sinf(ang);
        X[(size_t)rid * DMODEL + d] = a;
    }
}

// ---------------- generic C = A @ W^T + bias (optional relu) ----------------
// A: [M, lda] row-major (uses first K cols), W: [N, K] row-major, C: [M, N].
// Requires M%64==0, N%64==0, K%16==0.
__global__ __launch_bounds__(256) void gemm_bias(
    const float* __restrict__ A, int lda,
    const float* __restrict__ W,
    const float* __restrict__ bias,
    float* __restrict__ C,
    int N, int K, int relu)
{
    __shared__ float As[16][66];
    __shared__ float Ws[16][66];
    int tid = threadIdx.x;
    int tx = tid & 15, ty = tid >> 4;
    int bm = blockIdx.y, bn = blockIdx.x;
    int lr = tid >> 2;            // 0..63
    int lc = (tid & 3) << 2;      // 0,4,8,12
    const float* Ap = A + (size_t)(bm * 64 + lr) * lda + lc;
    const float* Wp = W + (size_t)(bn * 64 + lr) * K + lc;
    float acc[4][4] = {};
    for (int k0 = 0; k0 < K; k0 += 16) {
        float4 a4 = *(const float4*)(Ap + k0);
        float4 w4 = *(const float4*)(Wp + k0);
        __syncthreads();
        As[lc + 0][lr] = a4.x; As[lc + 1][lr] = a4.y;
        As[lc + 2][lr] = a4.z; As[lc + 3][lr] = a4.w;
        Ws[lc + 0][lr] = w4.x; Ws[lc + 1][lr] = w4.y;
        Ws[lc + 2][lr] = w4.z; Ws[lc + 3][lr] = w4.w;
        __syncthreads();
        #pragma unroll
        for (int k = 0; k < 16; k++) {
            float av[4], wv[4];
            #pragma unroll
            for (int i = 0; i < 4; i++) av[i] = As[k][ty * 4 + i];
            #pragma unroll
            for (int j = 0; j < 4; j++) wv[j] = Ws[k][tx * 4 + j];
            #pragma unroll
            for (int i = 0; i < 4; i++)
                #pragma unroll
                for (int j = 0; j < 4; j++)
                    acc[i][j] = fmaf(av[i], wv[j], acc[i][j]);
        }
    }
    #pragma unroll
    for (int i = 0; i < 4; i++) {
        int r = bm * 64 + ty * 4 + i;
        #pragma unroll
        for (int j = 0; j < 4; j++) {
            int c = bn * 64 + tx * 4 + j;
            float v = acc[i][j] + bias[c];
            if (relu) v = fmaxf(v, 0.f);
            C[(size_t)r * N + c] = v;
        }
    }
}

// ---------------- flash attention (fp32, causal + PRE block) ----------------
// QKV: [B*S, 1536]; q at col h*128, k at 512+h*128, v at 1024+h*128.
// Writes attention output IN PLACE over the Q columns.
// Block: 256 threads; thread t -> q row (t>>2) of the 64-row block, d-quarter (t&3).
__global__ __launch_bounds__(256) void flash_attn(float* __restrict__ QKV)
{
    __shared__ float Ks[64][DHEAD];
    __shared__ float Vs[64][DHEAD];
    int tid = threadIdx.x;
    int r = tid >> 2;
    int quarter = tid & 3;
    int qb = blockIdx.x, h = blockIdx.y, b = blockIdx.z;
    int qi = qb * 64 + r;
    size_t rowbase = ((size_t)b * S_LEN + qi) * 1536 + h * DHEAD + quarter * 32;
    float q[32], o[32];
    #pragma unroll
    for (int d = 0; d < 32; d++) { q[d] = QKV[rowbase + d]; o[d] = 0.f; }
    float m = -1e30f, l = 0.f;
    const float scale = 0.08838834764831845f;  // 1/sqrt(128)
    for (int kt = 0; kt <= qb; kt++) {
        __syncthreads();
        #pragma unroll
        for (int i = 0; i < 8; i++) {
            int idx4 = tid + i * 256;          // 0..2047 float4 slots
            int kr = idx4 >> 5;
            int kc = (idx4 & 31) << 2;
            size_t srcb = ((size_t)b * S_LEN + kt * 64 + kr) * 1536 + h * DHEAD + kc;
            *(float4*)&Ks[kr][kc] = *(const float4*)&QKV[srcb + 512];
            *(float4*)&Vs[kr][kc] = *(const float4*)&QKV[srcb + 1024];
        }
        __syncthreads();
        #pragma unroll 1
        for (int kc4 = 0; kc4 < 4; kc4++) {
            float p[16];
            float mt = -1e30f;
            #pragma unroll
            for (int kk = 0; kk < 16; kk++) {
                int k = kc4 * 16 + kk;
                const float* kp = &Ks[k][quarter * 32];
                float s = 0.f;
                #pragma unroll
                for (int d = 0; d < 32; d++) s = fmaf(q[d], kp[d], s);
                s += __shfl_xor(s, 1);
                s += __shfl_xor(s, 2);
                int kj = kt * 64 + k;
                bool ok = (kj <= qi) || (qi < PRE && kj < PRE);
                p[kk] = ok ? s * scale : -1e30f;
                mt = fmaxf(mt, p[kk]);
            }
            float mn = fmaxf(m, mt);
            float sc = expf(m - mn);
            float ls = 0.f;
            #pragma unroll
            for (int kk = 0; kk < 16; kk++) { float e = expf(p[kk] - mn); p[kk] = e; ls += e; }
            m = mn; l = l * sc + ls;
            #pragma unroll
            for (int d = 0; d < 32; d++) o[d] *= sc;
            #pragma unroll
            for (int kk = 0; kk < 16; kk++) {
                const float* vp = &Vs[kc4 * 16 + kk][quarter * 32];
                float pk = p[kk];
                #pragma unroll
                for (int d = 0; d < 32; d++) o[d] = fmaf(pk, vp[d], o[d]);
            }
        }
    }
    float inv = 1.f / l;
    #pragma unroll
    for (int d = 0; d < 32; d++) QKV[rowbase + d] = o[d] * inv;
}

// ---------------- X = LayerNorm(X + D) * g + b ----------------
__global__ __launch_bounds__(256) void add_ln_kernel(
    float* __restrict__ X, const float* __restrict__ D,
    const float* __restrict__ g, const float* __restrict__ bb)
{
    int row = blockIdx.x;
    int tid = threadIdx.x;
    size_t base = (size_t)row * DMODEL;
    float v0 = X[base + tid] + D[base + tid];
    float v1 = X[base + tid + 256] + D[base + tid + 256];
    float s = v0 + v1;
    float sq = v0 * v0 + v1 * v1;
    #pragma unroll
    for (int off = 32; off > 0; off >>= 1) {
        s  += __shfl_down(s, off);
        sq += __shfl_down(sq, off);
    }
    __shared__ float red[2][4];
    int wv = tid >> 6;
    if ((tid & 63) == 0) { red[0][wv] = s; red[1][wv] = sq; }
    __syncthreads();
    s  = red[0][0] + red[0][1] + red[0][2] + red[0][3];
    sq = red[1][0] + red[1][1] + red[1][2] + red[1][3];
    float mu = s * (1.f / DMODEL);
    float var = sq * (1.f / DMODEL) - mu * mu;
    float rs = rsqrtf(var + 1e-5f);
    X[base + tid]       = (v0 - mu) * rs * g[tid] + bb[tid];
    X[base + tid + 256] = (v1 - mu) * rs * g[tid + 256] + bb[tid + 256];
}

// ---------------- out = tanh(X @ dec_w^T + dec_b) * 10 ----------------
__global__ __launch_bounds__(256) void decoder_kernel(
    const float* __restrict__ X, const float* __restrict__ w,
    const float* __restrict__ bias, float* __restrict__ out)
{
    int tid = threadIdx.x;
    int lane = tid & 63;
    int row = blockIdx.x * 4 + (tid >> 6);
    float s = 0.f;
    size_t base = (size_t)row * DMODEL;
    #pragma unroll
    for (int i = 0; i < 8; i++) s = fmaf(X[base + lane + i * 64], w[lane + i * 64], s);
    #pragma unroll
    for (int off = 32; off > 0; off >>= 1) s += __shfl_down(s, off);
    if (lane == 0) out[row] = tanhf(s + bias[0]) * 10.0f;
}

extern "C" void kernel_launch(void* const* d_in, const int* in_sizes, int n_in,
                              void* d_out, int out_size, void* d_ws, size_t ws_size,
                              hipStream_t stream)
{
    const float* src   = (const float*)d_in[0];
    const float* emb_w = (const float*)d_in[1];
    const float* emb_b = (const float*)d_in[2];
    const float* in_w  = (const float*)d_in[3];
    const float* in_b  = (const float*)d_in[4];
    const float* out_w = (const float*)d_in[5];
    const float* out_b = (const float*)d_in[6];
    const float* ln1_g = (const float*)d_in[7];
    const float* ln1_b = (const float*)d_in[8];
    const float* ln2_g = (const float*)d_in[9];
    const float* ln2_b = (const float*)d_in[10];
    const float* ff1_w = (const float*)d_in[11];
    const float* ff1_b = (const float*)d_in[12];
    const float* ff2_w = (const float*)d_in[13];
    const float* ff2_b = (const float*)d_in[14];
    const float* dec_w = (const float*)d_in[15];
    const float* dec_b = (const float*)d_in[16];

    float* X  = (float*)d_ws;            // [8192, 512]   16 MB
    float* B1 = X + 8192 * 512;          // [8192, 2048]  64 MB  (QKV 1536 cols / FFN hidden 2048 cols)
    float* B3 = B1 + (size_t)8192 * 2048;// [8192, 512]   16 MB  (proj / ffn2 output)
    float* out = (float*)d_out;

    const int M = BATCH * S_LEN;         // 8192

    hipLaunchKernelGGL(embed_kernel, dim3(M), dim3(256), 0, stream, src, emb_w, emb_b, X);

    for (int l = 0; l < 3; l++) {
        // QKV = X @ in_w^T + in_b   [8192, 1536]
        hipLaunchKernelGGL(gemm_bias, dim3(1536 / 64, M / 64), dim3(256), 0, stream,
                           X, DMODEL, in_w + (size_t)l * 1536 * 512, in_b + l * 1536,
                           B1, 1536, 512, 0);
        // attention, writes O over Q columns of B1
        hipLaunchKernelGGL(flash_attn, dim3(S_LEN / 64, NHEADS, BATCH), dim3(256), 0, stream, B1);
        // O-proj: B3 = O @ out_w^T + out_b
        hipLaunchKernelGGL(gemm_bias, dim3(512 / 64, M / 64), dim3(256), 0, stream,
                           B1, 1536, out_w + (size_t)l * 512 * 512, out_b + l * 512,
                           B3, 512, 512, 0);
        hipLaunchKernelGGL(add_ln_kernel, dim3(M), dim3(256), 0, stream,
                           X, B3, ln1_g + l * 512, ln1_b + l * 512);
        // FFN1 (+relu): B1 = relu(X @ ff1_w^T + ff1_b)  [8192, 2048]
        hipLaunchKernelGGL(gemm_bias, dim3(2048 / 64, M / 64), dim3(256), 0, stream,
                           X, DMODEL, ff1_w + (size_t)l * 2048 * 512, ff1_b + l * 2048,
                           B1, 2048, 512, 1);
        // FFN2: B3 = B1 @ ff2_w^T + ff2_b
        hipLaunchKernelGGL(gemm_bias, dim3(512 / 64, M / 64), dim3(256), 0, stream,
                           B1, 2048, ff2_w + (size_t)l * 512 * 2048, ff2_b + l * 512,
                           B3, 512, 2048, 0);
        hipLaunchKernelGGL(add_ln_kernel, dim3(M), dim3(256), 0, stream,
                           X, B3, ln2_g + l * 512, ln2_b + l * 512);
    }

    hipLaunchKernelGGL(decoder_kernel, dim3(M / 4), dim3(256), 0, stream, X, dec_w, dec_b, out);
}

// Round 2
// 696.992 us; speedup vs baseline: 8.7319x; 8.7319x over previous
//
#include <hip/hip_runtime.h>

#define S_LEN 2048
#define DMODEL 512

typedef __attribute__((ext_vector_type(8))) short bf16x8;
typedef __attribute__((ext_vector_type(4))) float f32x4;
typedef __attribute__((ext_vector_type(4))) unsigned short u16x4;

__device__ __forceinline__ unsigned short f2bf(float f) {
    unsigned int u = __float_as_uint(f);
    u += 0x7fff + ((u >> 16) & 1);            // RNE
    return (unsigned short)(u >> 16);
}
__device__ __forceinline__ float bf2f(unsigned short h) {
    return __uint_as_float(((unsigned int)h) << 16);
}
__device__ __forceinline__ void gll16(const void* g, void* l) {
    __builtin_amdgcn_global_load_lds(
        (const __attribute__((address_space(1))) unsigned int*)g,
        (__attribute__((address_space(3))) unsigned int*)l, 16, 0, 0);
}

// ---------------- fp32 -> bf16 bulk convert (weights) ----------------
__global__ __launch_bounds__(256) void conv_bf16(const float4* __restrict__ in,
                                                 u16x4* __restrict__ out)
{
    int i = blockIdx.x * 256 + threadIdx.x;
    float4 v = in[i];
    u16x4 o = { f2bf(v.x), f2bf(v.y), f2bf(v.z), f2bf(v.w) };
    out[i] = o;
}

// ---------------- embedding + positional encoding ----------------
__global__ __launch_bounds__(256) void embed_kernel(
    const float* __restrict__ src, const float* __restrict__ ew,
    const float* __restrict__ eb, float* __restrict__ X,
    unsigned short* __restrict__ Xb)
{
    int rid = blockIdx.x;              // b*S + s
    int s = rid & (S_LEN - 1);
    int tid = threadIdx.x;
    __shared__ float sr[25];
    if (tid < 25) sr[tid] = src[rid * 25 + tid];
    __syncthreads();
    #pragma unroll
    for (int rep = 0; rep < 2; rep++) {
        int d = tid + rep * 256;
        float a = eb[d];
        #pragma unroll
        for (int k = 0; k < 25; k++) a = fmaf(sr[k], ew[d * 25 + k], a);
        int i2 = d & ~1;
        float div = expf(-(float)i2 * (9.210340371976184f / 512.f));
        float ang = (float)s * div;
        a += (d & 1) ? cosf(ang) : sinf(ang);
        X[(size_t)rid * DMODEL + d] = a;
        Xb[(size_t)rid * DMODEL + d] = f2bf(a);
    }
}

// ---------------- bf16 MFMA GEMM: C = A @ W^T + bias ----------------
// A: [M][lda] bf16, W: [N][K] bf16, 128x128 tile, BK=64, 4 waves (2x2).
// MODE 1: bf16 out; MODE 2: bf16 out + relu; MODE 3: QKV split (cols<1024 ->
// out (ldc=1024), cols>=1024 -> V transposed into out2[b][h][d][t]).
template<int MODE>
__global__ __launch_bounds__(256) void gemm_bf16(
    const unsigned short* __restrict__ A, int lda,
    const unsigned short* __restrict__ W, int K,
    const float* __restrict__ bias,
    unsigned short* __restrict__ out, int ldc,
    unsigned short* __restrict__ out2)
{
    __shared__ __align__(16) unsigned short As[128 * 64];
    __shared__ __align__(16) unsigned short Ws[128 * 64];
    int tid = threadIdx.x;
    int lane = tid & 63, w = tid >> 6;
    int g = lane >> 4, c15 = lane & 15;
    int wm = w >> 1, wn = w & 1;
    int bm = blockIdx.y, bn = blockIdx.x;

    f32x4 acc[4][4];
    #pragma unroll
    for (int i = 0; i < 4; i++)
        #pragma unroll
        for (int j = 0; j < 4; j++) acc[i][j] = (f32x4){0.f, 0.f, 0.f, 0.f};

    const int nk = K >> 6;
    for (int kk = 0; kk < nk; kk++) {
        __syncthreads();
        #pragma unroll
        for (int i = 0; i < 4; i++) {        // stage A tile: 128x64, swizzled src
            int chunk = tid + i * 256;
            int r = chunk >> 3, c = chunk & 7;
            int cs = c ^ (r & 7);
            gll16(A + (size_t)(bm * 128 + r) * lda + kk * 64 + cs * 8,
                  (void*)(As + chunk * 8));
        }
        #pragma unroll
        for (int i = 0; i < 4; i++) {        // stage W tile
            int chunk = tid + i * 256;
            int r = chunk >> 3, c = chunk & 7;
            int cs = c ^ (r & 7);
            gll16(W + (size_t)(bn * 128 + r) * K + kk * 64 + cs * 8,
                  (void*)(Ws + chunk * 8));
        }
        __syncthreads();
        bf16x8 a[4][2], b[4][2];
        #pragma unroll
        for (int mi = 0; mi < 4; mi++) {
            int row = wm * 64 + mi * 16 + c15;
            #pragma unroll
            for (int h = 0; h < 2; h++) {
                int ck = (h * 4 + g) ^ (row & 7);
                a[mi][h] = *(const bf16x8*)((const char*)As + row * 128 + ck * 16);
            }
        }
        #pragma unroll
        for (int nj = 0; nj < 4; nj++) {
            int row = wn * 64 + nj * 16 + c15;
            #pragma unroll
            for (int h = 0; h < 2; h++) {
                int ck = (h * 4 + g) ^ (row & 7);
                b[nj][h] = *(const bf16x8*)((const char*)Ws + row * 128 + ck * 16);
            }
        }
        #pragma unroll
        for (int h = 0; h < 2; h++)
            #pragma unroll
            for (int mi = 0; mi < 4; mi++)
                #pragma unroll
                for (int nj = 0; nj < 4; nj++)
                    acc[mi][nj] = __builtin_amdgcn_mfma_f32_16x16x32_bf16(
                        a[mi][h], b[nj][h], acc[mi][nj], 0, 0, 0);
    }
    // epilogue: C row = (lane>>4)*4 + reg, col = lane&15 (HW-verified layout)
    #pragma unroll
    for (int nj = 0; nj < 4; nj++) {
        int colb = bn * 128 + wn * 64 + nj * 16;
        float bv = bias[colb + c15];
        #pragma unroll
        for (int mi = 0; mi < 4; mi++) {
            int rowb = bm * 128 + wm * 64 + mi * 16 + g * 4;
            if (MODE == 3 && colb >= 1024) {     // V -> transposed global
                int cv = colb - 1024 + c15;
                int hh = cv >> 7, d = cv & 127;
                int bb = rowb >> 11, t = rowb & (S_LEN - 1);
                u16x4 pk;
                #pragma unroll
                for (int r = 0; r < 4; r++) pk[r] = f2bf(acc[mi][nj][r] + bv);
                *(u16x4*)(out2 + ((size_t)(bb * 4 + hh) * 128 + d) * S_LEN + t) = pk;
            } else {
                #pragma unroll
                for (int r = 0; r < 4; r++) {
                    float v = acc[mi][nj][r] + bv;
                    if (MODE == 2) v = fmaxf(v, 0.f);
                    out[(size_t)(rowb + r) * ldc + colb + c15] = f2bf(v);
                }
            }
        }
    }
}

// ---------------- bf16 MFMA flash attention ----------------
// QKb: [B*S][1024] (q: h*128, k: 512+h*128), Vt: [B*H][128][2048], Ob: [B*S][512]
__global__ __launch_bounds__(256) void flash_attn(
    const unsigned short* __restrict__ QKb,
    const unsigned short* __restrict__ Vt,
    unsigned short* __restrict__ Ob)
{
    __shared__ __align__(16) unsigned short Ks[64 * 128];
    __shared__ __align__(16) unsigned short Vts[128 * 64];
    __shared__ __align__(16) unsigned short Plds[4][16 * 72];  // stride 72: pad
    int tid = threadIdx.x;
    int lane = tid & 63, w = tid >> 6;
    int g = lane >> 4, c15 = lane & 15;
    int h = blockIdx.y, b = blockIdx.z;
    int qb = (blockIdx.x + 11 * (blockIdx.y + 4 * blockIdx.z)) & 31;  // balance mix
    int qr0 = qb * 64 + w * 16;

    bf16x8 q[4];
    {
        const unsigned short* qrow = QKb + (size_t)(b * S_LEN + qr0 + c15) * 1024 + h * 128;
        #pragma unroll
        for (int k0 = 0; k0 < 4; k0++)
            q[k0] = *(const bf16x8*)(qrow + k0 * 32 + g * 8);
    }
    f32x4 o[8];
    #pragma unroll
    for (int cd = 0; cd < 8; cd++) o[cd] = (f32x4){0.f, 0.f, 0.f, 0.f};
    float m[4], l[4];
    #pragma unroll
    for (int r = 0; r < 4; r++) { m[r] = -1e30f; l[r] = 0.f; }
    const float scale = 0.08838834764831845f;   // 1/sqrt(128)

    for (int kt = 0; kt <= qb; kt++) {
        __syncthreads();
        #pragma unroll
        for (int i = 0; i < 4; i++) {      // K tile: 64 rows x 16 chunks
            int chunk = tid + i * 256;
            int r = chunk >> 4, c = chunk & 15;
            int cs = (c & 8) | ((c ^ r) & 7);
            gll16(QKb + (size_t)(b * S_LEN + kt * 64 + r) * 1024 + 512 + h * 128 + cs * 8,
                  (void*)(Ks + chunk * 8));
        }
        #pragma unroll
        for (int i = 0; i < 4; i++) {      // Vt tile: 128 rows x 8 chunks
            int chunk = tid + i * 256;
            int r = chunk >> 3, c = chunk & 7;
            int cs = (c ^ r) & 7;
            gll16(Vt + ((size_t)(b * 4 + h) * 128 + r) * S_LEN + kt * 64 + cs * 8,
                  (void*)(Vts + chunk * 8));
        }
        __syncthreads();
        // --- S = Q K^T ---
        f32x4 sf[4];
        #pragma unroll
        for (int c = 0; c < 4; c++) {
            sf[c] = (f32x4){0.f, 0.f, 0.f, 0.f};
            int tok = c * 16 + c15;
            #pragma unroll
            for (int k0 = 0; k0 < 4; k0++) {
                int ck = k0 * 4 + g;
                int cs = (ck & 8) | ((ck ^ tok) & 7);
                bf16x8 kf = *(const bf16x8*)((const char*)Ks + tok * 256 + cs * 16);
                sf[c] = __builtin_amdgcn_mfma_f32_16x16x32_bf16(q[k0], kf, sf[c], 0, 0, 0);
            }
        }
        // --- mask + scale + row max ---
        float mt[4];
        #pragma unroll
        for (int r = 0; r < 4; r++) mt[r] = -1e30f;
        int qi = qr0 + g * 4;
        #pragma unroll
        for (int c = 0; c < 4; c++) {
            int tok = kt * 64 + c * 16 + c15;
            #pragma unroll
            for (int r = 0; r < 4; r++) {
                int qr = qi + r;
                bool ok = (tok <= qr) || (qr < 20 && tok < 20);
                float v = ok ? sf[c][r] * scale : -1e30f;
                sf[c][r] = v;
                mt[r] = fmaxf(mt[r], v);
            }
        }
        #pragma unroll
        for (int r = 0; r < 4; r++) {
            #pragma unroll
            for (int off = 1; off < 16; off <<= 1)
                mt[r] = fmaxf(mt[r], __shfl_xor(mt[r], off));
        }
        float sc[4], ls[4];
        #pragma unroll
        for (int r = 0; r < 4; r++) {
            float mn = fmaxf(m[r], mt[r]);
            sc[r] = __expf(m[r] - mn);
            m[r] = mn;
            ls[r] = 0.f;
        }
        #pragma unroll
        for (int c = 0; c < 4; c++) {
            #pragma unroll
            for (int r = 0; r < 4; r++) {
                float e = __expf(sf[c][r] - m[r]);
                sf[c][r] = e;
                ls[r] += e;
            }
        }
        #pragma unroll
        for (int r = 0; r < 4; r++) {
            float t = ls[r];
            #pragma unroll
            for (int off = 1; off < 16; off <<= 1) t += __shfl_xor(t, off);
            l[r] = l[r] * sc[r] + t;
        }
        // --- P -> bf16 via per-wave LDS scratch ---
        #pragma unroll
        for (int c = 0; c < 4; c++)
            #pragma unroll
            for (int r = 0; r < 4; r++)
                Plds[w][(g * 4 + r) * 72 + c * 16 + c15] = f2bf(sf[c][r]);
        // --- rescale O ---
        #pragma unroll
        for (int cd = 0; cd < 8; cd++)
            #pragma unroll
            for (int r = 0; r < 4; r++)
                o[cd][r] *= sc[r];
        // --- O += P V ---
        bf16x8 pa[2];
        #pragma unroll
        for (int k0 = 0; k0 < 2; k0++)
            pa[k0] = *(const bf16x8*)((const char*)&Plds[w][0] + c15 * 144 + k0 * 64 + g * 16);
        #pragma unroll
        for (int cd = 0; cd < 8; cd++) {
            int dv = cd * 16 + c15;
            #pragma unroll
            for (int k0 = 0; k0 < 2; k0++) {
                int ck = k0 * 4 + g;
                int cs = (ck ^ dv) & 7;
                bf16x8 vf = *(const bf16x8*)((const char*)Vts + dv * 128 + cs * 16);
                o[cd] = __builtin_amdgcn_mfma_f32_16x16x32_bf16(pa[k0], vf, o[cd], 0, 0, 0);
            }
        }
    }
    #pragma unroll
    for (int r = 0; r < 4; r++) l[r] = 1.f / l[r];
    size_t obase = (size_t)(b * S_LEN + qr0 + g * 4) * 512 + h * 128;
    #pragma unroll
    for (int cd = 0; cd < 8; cd++)
        #pragma unroll
        for (int r = 0; r < 4; r++)
            Ob[obase + (size_t)r * 512 + cd * 16 + c15] = f2bf(o[cd][r] * l[r]);
}

// ---------------- X = LayerNorm(X + D)*g + b ;  Xb = bf16(X) ----------------
__global__ __launch_bounds__(256) void add_ln_kernel(
    float* __restrict__ X, const unsigned short* __restrict__ D,
    const float* __restrict__ gw, const float* __restrict__ bw,
    unsigned short* __restrict__ Xb)
{
    int row = blockIdx.x;
    int tid = threadIdx.x;
    size_t base = (size_t)row * DMODEL;
    float v0 = X[base + tid] + bf2f(D[base + tid]);
    float v1 = X[base + tid + 256] + bf2f(D[base + tid + 256]);
    float s = v0 + v1;
    float sq = v0 * v0 + v1 * v1;
    #pragma unroll
    for (int off = 32; off > 0; off >>= 1) {
        s  += __shfl_down(s, off);
        sq += __shfl_down(sq, off);
    }
    __shared__ float red[2][4];
    int wv = tid >> 6;
    if ((tid & 63) == 0) { red[0][wv] = s; red[1][wv] = sq; }
    __syncthreads();
    s  = red[0][0] + red[0][1] + red[0][2] + red[0][3];
    sq = red[1][0] + red[1][1] + red[1][2] + red[1][3];
    float mu = s * (1.f / DMODEL);
    float var = sq * (1.f / DMODEL) - mu * mu;
    float rs = rsqrtf(var + 1e-5f);
    float y0 = (v0 - mu) * rs * gw[tid] + bw[tid];
    float y1 = (v1 - mu) * rs * gw[tid + 256] + bw[tid + 256];
    X[base + tid] = y0;
    X[base + tid + 256] = y1;
    Xb[base + tid] = f2bf(y0);
    Xb[base + tid + 256] = f2bf(y1);
}

// ---------------- out = tanh(X @ dec_w^T + dec_b) * 10 ----------------
__global__ __launch_bounds__(256) void decoder_kernel(
    const float* __restrict__ X, const float* __restrict__ w,
    const float* __restrict__ bias, float* __restrict__ out)
{
    int tid = threadIdx.x;
    int lane = tid & 63;
    int row = blockIdx.x * 4 + (tid >> 6);
    float s = 0.f;
    size_t base = (size_t)row * DMODEL;
    #pragma unroll
    for (int i = 0; i < 8; i++) s = fmaf(X[base + lane + i * 64], w[lane + i * 64], s);
    #pragma unroll
    for (int off = 32; off > 0; off >>= 1) s += __shfl_down(s, off);
    if (lane == 0) out[row] = tanhf(s + bias[0]) * 10.0f;
}

extern "C" void kernel_launch(void* const* d_in, const int* in_sizes, int n_in,
                              void* d_out, int out_size, void* d_ws, size_t ws_size,
                              hipStream_t stream)
{
    const float* src   = (const float*)d_in[0];
    const float* emb_w = (const float*)d_in[1];
    const float* emb_b = (const float*)d_in[2];
    const float* in_w  = (const float*)d_in[3];
    const float* in_b  = (const float*)d_in[4];
    const float* out_w = (const float*)d_in[5];
    const float* out_b = (const float*)d_in[6];
    const float* ln1_g = (const float*)d_in[7];
    const float* ln1_b = (const float*)d_in[8];
    const float* ln2_g = (const float*)d_in[9];
    const float* ln2_b = (const float*)d_in[10];
    const float* ff1_w = (const float*)d_in[11];
    const float* ff1_b = (const float*)d_in[12];
    const float* ff2_w = (const float*)d_in[13];
    const float* ff2_b = (const float*)d_in[14];
    const float* dec_w = (const float*)d_in[15];
    const float* dec_b = (const float*)d_in[16];

    char* ws = (char*)d_ws;
    float*          X   = (float*)ws;                              // 16 MB
    unsigned short* Xb  = (unsigned short*)(ws + (16u << 20));     //  8 MB
    unsigned short* Pb  = (unsigned short*)(ws + (24u << 20));     //  8 MB
    unsigned short* Ob  = (unsigned short*)(ws + (32u << 20));     //  8 MB
    unsigned short* QKb = (unsigned short*)(ws + (40u << 20));     // 16 MB
    unsigned short* Vt  = (unsigned short*)(ws + (56u << 20));     //  8 MB
    unsigned short* Hb  = (unsigned short*)(ws + (40u << 20));     // 32 MB (overlaps QKb+Vt, disjoint in time)
    unsigned short* in_wb  = (unsigned short*)(ws + (72u << 20));
    unsigned short* out_wb = in_wb  + 3u * 1536 * 512;
    unsigned short* ff1_wb = out_wb + 3u * 512 * 512;
    unsigned short* ff2_wb = ff1_wb + 3u * 2048 * 512;
    float* outp = (float*)d_out;
    const int M = 4 * S_LEN;   // 8192

    conv_bf16<<<2304, 256, 0, stream>>>((const float4*)in_w,  (u16x4*)in_wb);
    conv_bf16<<<768,  256, 0, stream>>>((const float4*)out_w, (u16x4*)out_wb);
    conv_bf16<<<3072, 256, 0, stream>>>((const float4*)ff1_w, (u16x4*)ff1_wb);
    conv_bf16<<<3072, 256, 0, stream>>>((const float4*)ff2_w, (u16x4*)ff2_wb);

    embed_kernel<<<M, 256, 0, stream>>>(src, emb_w, emb_b, X, Xb);

    for (int l = 0; l < 3; l++) {
        gemm_bf16<3><<<dim3(12, 64), 256, 0, stream>>>(
            Xb, 512, in_wb + (size_t)l * 1536 * 512, 512, in_b + l * 1536,
            QKb, 1024, Vt);
        flash_attn<<<dim3(32, 4, 4), 256, 0, stream>>>(QKb, Vt, Ob);
        gemm_bf16<1><<<dim3(4, 64), 256, 0, stream>>>(
            Ob, 512, out_wb + (size_t)l * 512 * 512, 512, out_b + l * 512,
            Pb, 512, nullptr);
        add_ln_kernel<<<M, 256, 0, stream>>>(X, Pb, ln1_g + l * 512, ln1_b + l * 512, Xb);
        gemm_bf16<2><<<dim3(16, 64), 256, 0, stream>>>(
            Xb, 512, ff1_wb + (size_t)l * 2048 * 512, 512, ff1_b + l * 2048,
            Hb, 2048, nullptr);
        gemm_bf16<1><<<dim3(4, 64), 256, 0, stream>>>(
            Hb, 2048, ff2_wb + (size_t)l * 512 * 2048, 2048, ff2_b + l * 512,
            Pb, 512, nullptr);
        add_ln_kernel<<<M, 256, 0, stream>>>(X, Pb, ln2_g + l * 512, ln2_b + l * 512, Xb);
    }

    decoder_kernel<<<M / 4, 256, 0, stream>>>(X, dec_w, dec_b, outp);
}

// Round 3
// 621.643 us; speedup vs baseline: 9.7903x; 1.1212x over previous
//
#include <hip/hip_runtime.h>

#define S_LEN 2048
#define DMODEL 512

typedef __attribute__((ext_vector_type(8))) short bf16x8;
typedef __attribute__((ext_vector_type(4))) float f32x4;
typedef __attribute__((ext_vector_type(4))) unsigned short u16x4;

__device__ __forceinline__ unsigned short f2bf(float f) {
    unsigned int u = __float_as_uint(f);
    u += 0x7fff + ((u >> 16) & 1);            // RNE
    return (unsigned short)(u >> 16);
}
__device__ __forceinline__ float bf2f(unsigned short h) {
    return __uint_as_float(((unsigned int)h) << 16);
}
__device__ __forceinline__ void gll16(const void* g, void* l) {
    __builtin_amdgcn_global_load_lds(
        (const __attribute__((address_space(1))) unsigned int*)g,
        (__attribute__((address_space(3))) unsigned int*)l, 16, 0, 0);
}

// ---------------- fp32 -> bf16 bulk convert (weights) ----------------
__global__ __launch_bounds__(256) void conv_bf16(const float4* __restrict__ in,
                                                 u16x4* __restrict__ out)
{
    int i = blockIdx.x * 256 + threadIdx.x;
    float4 v = in[i];
    u16x4 o = { f2bf(v.x), f2bf(v.y), f2bf(v.z), f2bf(v.w) };
    out[i] = o;
}

// ---------------- embedding + positional encoding ----------------
__global__ __launch_bounds__(256) void embed_kernel(
    const float* __restrict__ src, const float* __restrict__ ew,
    const float* __restrict__ eb, float* __restrict__ X,
    unsigned short* __restrict__ Xb)
{
    int rid = blockIdx.x;              // b*S + s
    int s = rid & (S_LEN - 1);
    int tid = threadIdx.x;
    __shared__ float sr[25];
    if (tid < 25) sr[tid] = src[rid * 25 + tid];
    __syncthreads();
    #pragma unroll
    for (int rep = 0; rep < 2; rep++) {
        int d = tid + rep * 256;
        float a = eb[d];
        #pragma unroll
        for (int k = 0; k < 25; k++) a = fmaf(sr[k], ew[d * 25 + k], a);
        int i2 = d & ~1;
        float div = expf(-(float)i2 * (9.210340371976184f / 512.f));
        float ang = (float)s * div;
        a += (d & 1) ? cosf(ang) : sinf(ang);
        X[(size_t)rid * DMODEL + d] = a;
        Xb[(size_t)rid * DMODEL + d] = f2bf(a);
    }
}

// ---------------- bf16 MFMA GEMM: C = A @ W^T + bias ----------------
// A: [M][lda] bf16, W: [N][K] bf16, 128xBN tile, BK=64, 4 waves (2x2).
// MODE 1: bf16 out; MODE 2: bf16 out + relu; MODE 3: QKV split (cols<1024 ->
// out (ldc=1024), cols>=1024 -> V transposed into out2[b][h][d][t]).
// BN=64 path uses a 1D grid of 512 blocks with XCD-chunked decode.
template<int MODE, int BN>
__global__ __launch_bounds__(256) void gemm_bf16(
    const unsigned short* __restrict__ A, int lda,
    const unsigned short* __restrict__ W, int K,
    const float* __restrict__ bias,
    unsigned short* __restrict__ out, int ldc,
    unsigned short* __restrict__ out2)
{
    constexpr int NJ = BN / 32;
    __shared__ __align__(16) unsigned short As[128 * 64];
    __shared__ __align__(16) unsigned short Ws[BN * 64];
    int tid = threadIdx.x;
    int lane = tid & 63, w = tid >> 6;
    int g = lane >> 4, c15 = lane & 15;
    int wm = w >> 1, wn = w & 1;
    int bm, bn;
    if (BN == 64) {
        int raw = blockIdx.x;
        int lid = ((raw & 7) << 6) | (raw >> 3);  // consecutive lid -> same XCD
        bn = lid & 7; bm = lid >> 3;              // 8 bn-blocks share A panel on one XCD
    } else {
        bm = blockIdx.y; bn = blockIdx.x;
    }

    f32x4 acc[4][NJ];
    #pragma unroll
    for (int i = 0; i < 4; i++)
        #pragma unroll
        for (int j = 0; j < NJ; j++) acc[i][j] = (f32x4){0.f, 0.f, 0.f, 0.f};

    const int nk = K >> 6;
    for (int kk = 0; kk < nk; kk++) {
        __syncthreads();
        #pragma unroll
        for (int i = 0; i < 4; i++) {        // stage A tile: 128x64, swizzled src
            int chunk = tid + i * 256;
            int r = chunk >> 3, c = chunk & 7;
            int cs = c ^ (r & 7);
            gll16(A + (size_t)(bm * 128 + r) * lda + kk * 64 + cs * 8,
                  (void*)(As + chunk * 8));
        }
        #pragma unroll
        for (int i = 0; i < BN / 32; i++) {  // stage W tile: BNx64
            int chunk = tid + i * 256;
            int r = chunk >> 3, c = chunk & 7;
            int cs = c ^ (r & 7);
            gll16(W + (size_t)(bn * BN + r) * K + kk * 64 + cs * 8,
                  (void*)(Ws + chunk * 8));
        }
        __syncthreads();
        bf16x8 a[4][2], b[NJ][2];
        #pragma unroll
        for (int mi = 0; mi < 4; mi++) {
            int row = wm * 64 + mi * 16 + c15;
            #pragma unroll
            for (int h = 0; h < 2; h++) {
                int ck = (h * 4 + g) ^ (row & 7);
                a[mi][h] = *(const bf16x8*)((const char*)As + row * 128 + ck * 16);
            }
        }
        #pragma unroll
        for (int nj = 0; nj < NJ; nj++) {
            int row = wn * (BN / 2) + nj * 16 + c15;
            #pragma unroll
            for (int h = 0; h < 2; h++) {
                int ck = (h * 4 + g) ^ (row & 7);
                b[nj][h] = *(const bf16x8*)((const char*)Ws + row * 128 + ck * 16);
            }
        }
        __builtin_amdgcn_s_setprio(1);
        #pragma unroll
        for (int h = 0; h < 2; h++)
            #pragma unroll
            for (int mi = 0; mi < 4; mi++)
                #pragma unroll
                for (int nj = 0; nj < NJ; nj++)
                    acc[mi][nj] = __builtin_amdgcn_mfma_f32_16x16x32_bf16(
                        a[mi][h], b[nj][h], acc[mi][nj], 0, 0, 0);
        __builtin_amdgcn_s_setprio(0);
    }
    // epilogue: C row = (lane>>4)*4 + reg, col = lane&15 (HW-verified layout)
    #pragma unroll
    for (int nj = 0; nj < NJ; nj++) {
        int colb = bn * BN + wn * (BN / 2) + nj * 16;
        float bv = bias[colb + c15];
        #pragma unroll
        for (int mi = 0; mi < 4; mi++) {
            int rowb = bm * 128 + wm * 64 + mi * 16 + g * 4;
            if (MODE == 3 && colb >= 1024) {     // V -> transposed global
                int cv = colb - 1024 + c15;
                int hh = cv >> 7, d = cv & 127;
                int bb = rowb >> 11, t = rowb & (S_LEN - 1);
                u16x4 pk;
                #pragma unroll
                for (int r = 0; r < 4; r++) pk[r] = f2bf(acc[mi][nj][r] + bv);
                *(u16x4*)(out2 + ((size_t)(bb * 4 + hh) * 128 + d) * S_LEN + t) = pk;
            } else {
                #pragma unroll
                for (int r = 0; r < 4; r++) {
                    float v = acc[mi][nj][r] + bv;
                    if (MODE == 2) v = fmaxf(v, 0.f);
                    out[(size_t)(rowb + r) * ldc + colb + c15] = f2bf(v);
                }
            }
        }
    }
}

// ---------------- bf16 MFMA flash attention (2-phase pipelined) ----------------
// QKb: [B*S][1024] (q: h*128, k: 512+h*128), Vt: [B*H][128][2048], Ob: [B*S][512]
__global__ __launch_bounds__(256) void flash_attn(
    const unsigned short* __restrict__ QKb,
    const unsigned short* __restrict__ Vt,
    unsigned short* __restrict__ Ob)
{
    __shared__ __align__(16) unsigned short Ks[2][64 * 128];
    __shared__ __align__(16) unsigned short Vts[2][128 * 64];
    __shared__ __align__(16) unsigned short Plds[4][16 * 72];  // stride 72: pad
    int tid = threadIdx.x;
    int lane = tid & 63, w = tid >> 6;
    int g = lane >> 4, c15 = lane & 15;
    // XCD-chunked decode + complementary qb pairing for load balance:
    // consecutive lid share an XCD; co-resident blocks (lid, lid+32) have
    // qb sums == 31 -> every CU gets ~33 KV-tiles.
    int raw = blockIdx.x;
    int lid = ((raw & 7) << 6) | (raw >> 3);
    int x = lid & 31, hb = lid >> 5;
    int h = hb & 3, b = hb >> 2;
    int qb = (hb & 1) ? (31 - x) : x;
    int qr0 = qb * 64 + w * 16;

    bf16x8 q[4];
    {
        const unsigned short* qrow = QKb + (size_t)(b * S_LEN + qr0 + c15) * 1024 + h * 128;
        #pragma unroll
        for (int k0 = 0; k0 < 4; k0++)
            q[k0] = *(const bf16x8*)(qrow + k0 * 32 + g * 8);
    }
    f32x4 o[8];
    #pragma unroll
    for (int cd = 0; cd < 8; cd++) o[cd] = (f32x4){0.f, 0.f, 0.f, 0.f};
    float m[4], l[4];
    #pragma unroll
    for (int r = 0; r < 4; r++) { m[r] = -1e30f; l[r] = 0.f; }
    const float scale = 0.08838834764831845f;   // 1/sqrt(128)

    auto stage = [&](int kt, int bi) {
        #pragma unroll
        for (int i = 0; i < 4; i++) {      // K tile: 64 rows x 16 chunks
            int chunk = tid + i * 256;
            int r = chunk >> 4, c = chunk & 15;
            int cs = (c & 8) | ((c ^ r) & 7);
            gll16(QKb + (size_t)(b * S_LEN + kt * 64 + r) * 1024 + 512 + h * 128 + cs * 8,
                  (void*)(Ks[bi] + chunk * 8));
        }
        #pragma unroll
        for (int i = 0; i < 4; i++) {      // Vt tile: 128 rows x 8 chunks
            int chunk = tid + i * 256;
            int r = chunk >> 3, c = chunk & 7;
            int cs = (c ^ r) & 7;
            gll16(Vt + ((size_t)(b * 4 + h) * 128 + r) * S_LEN + kt * 64 + cs * 8,
                  (void*)(Vts[bi] + chunk * 8));
        }
    };

    stage(0, 0);
    __syncthreads();          // drains vmcnt(0) + barrier
    int buf = 0;

    for (int kt = 0; kt <= qb; kt++) {
        if (kt < qb) stage(kt + 1, buf ^ 1);   // prefetch next tile (overlaps compute)
        // --- S = Q K^T ---
        f32x4 sf[4];
        __builtin_amdgcn_s_setprio(1);
        #pragma unroll
        for (int c = 0; c < 4; c++) {
            sf[c] = (f32x4){0.f, 0.f, 0.f, 0.f};
            int tok = c * 16 + c15;
            #pragma unroll
            for (int k0 = 0; k0 < 4; k0++) {
                int ck = k0 * 4 + g;
                int cs = (ck & 8) | ((ck ^ tok) & 7);
                bf16x8 kf = *(const bf16x8*)((const char*)Ks[buf] + tok * 256 + cs * 16);
                sf[c] = __builtin_amdgcn_mfma_f32_16x16x32_bf16(q[k0], kf, sf[c], 0, 0, 0);
            }
        }
        __builtin_amdgcn_s_setprio(0);
        // --- mask + scale + row max ---
        float mt[4];
        #pragma unroll
        for (int r = 0; r < 4; r++) mt[r] = -1e30f;
        int qi = qr0 + g * 4;
        #pragma unroll
        for (int c = 0; c < 4; c++) {
            int tok = kt * 64 + c * 16 + c15;
            #pragma unroll
            for (int r = 0; r < 4; r++) {
                int qr = qi + r;
                bool ok = (tok <= qr) || (qr < 20 && tok < 20);
                float v = ok ? sf[c][r] * scale : -1e30f;
                sf[c][r] = v;
                mt[r] = fmaxf(mt[r], v);
            }
        }
        #pragma unroll
        for (int r = 0; r < 4; r++) {
            #pragma unroll
            for (int off = 1; off < 16; off <<= 1)
                mt[r] = fmaxf(mt[r], __shfl_xor(mt[r], off));
        }
        float sc[4], ls[4];
        #pragma unroll
        for (int r = 0; r < 4; r++) {
            float mn = fmaxf(m[r], mt[r]);
            sc[r] = __expf(m[r] - mn);
            m[r] = mn;
            ls[r] = 0.f;
        }
        #pragma unroll
        for (int c = 0; c < 4; c++) {
            #pragma unroll
            for (int r = 0; r < 4; r++) {
                float e = __expf(sf[c][r] - m[r]);
                sf[c][r] = e;
                ls[r] += e;
            }
        }
        #pragma unroll
        for (int r = 0; r < 4; r++) {
            float t = ls[r];
            #pragma unroll
            for (int off = 1; off < 16; off <<= 1) t += __shfl_xor(t, off);
            l[r] = l[r] * sc[r] + t;
        }
        // --- P -> bf16 via per-wave LDS scratch ---
        #pragma unroll
        for (int c = 0; c < 4; c++)
            #pragma unroll
            for (int r = 0; r < 4; r++)
                Plds[w][(g * 4 + r) * 72 + c * 16 + c15] = f2bf(sf[c][r]);
        // --- rescale O ---
        #pragma unroll
        for (int cd = 0; cd < 8; cd++)
            #pragma unroll
            for (int r = 0; r < 4; r++)
                o[cd][r] *= sc[r];
        // --- O += P V ---
        bf16x8 pa[2];
        #pragma unroll
        for (int k0 = 0; k0 < 2; k0++)
            pa[k0] = *(const bf16x8*)((const char*)&Plds[w][0] + c15 * 144 + k0 * 64 + g * 16);
        __builtin_amdgcn_s_setprio(1);
        #pragma unroll
        for (int cd = 0; cd < 8; cd++) {
            int dv = cd * 16 + c15;
            #pragma unroll
            for (int k0 = 0; k0 < 2; k0++) {
                int ck = k0 * 4 + g;
                int cs = (ck ^ dv) & 7;
                bf16x8 vf = *(const bf16x8*)((const char*)Vts[buf] + dv * 128 + cs * 16);
                o[cd] = __builtin_amdgcn_mfma_f32_16x16x32_bf16(pa[k0], vf, o[cd], 0, 0, 0);
            }
        }
        __builtin_amdgcn_s_setprio(0);
        __syncthreads();      // drains prefetch vmcnt + syncs buffer handoff
        buf ^= 1;
    }
    #pragma unroll
    for (int r = 0; r < 4; r++) l[r] = 1.f / l[r];
    size_t obase = (size_t)(b * S_LEN + qr0 + g * 4) * 512 + h * 128;
    #pragma unroll
    for (int cd = 0; cd < 8; cd++)
        #pragma unroll
        for (int r = 0; r < 4; r++)
            Ob[obase + (size_t)r * 512 + cd * 16 + c15] = f2bf(o[cd][r] * l[r]);
}

// ---------------- X = LayerNorm(X + D)*g + b ;  Xb = bf16(X) ----------------
__global__ __launch_bounds__(256) void add_ln_kernel(
    float* __restrict__ X, const unsigned short* __restrict__ D,
    const float* __restrict__ gw, const float* __restrict__ bw,
    unsigned short* __restrict__ Xb)
{
    int row = blockIdx.x;
    int tid = threadIdx.x;
    size_t base = (size_t)row * DMODEL;
    float v0 = X[base + tid] + bf2f(D[base + tid]);
    float v1 = X[base + tid + 256] + bf2f(D[base + tid + 256]);
    float s = v0 + v1;
    float sq = v0 * v0 + v1 * v1;
    #pragma unroll
    for (int off = 32; off > 0; off >>= 1) {
        s  += __shfl_down(s, off);
        sq += __shfl_down(sq, off);
    }
    __shared__ float red[2][4];
    int wv = tid >> 6;
    if ((tid & 63) == 0) { red[0][wv] = s; red[1][wv] = sq; }
    __syncthreads();
    s  = red[0][0] + red[0][1] + red[0][2] + red[0][3];
    sq = red[1][0] + red[1][1] + red[1][2] + red[1][3];
    float mu = s * (1.f / DMODEL);
    float var = sq * (1.f / DMODEL) - mu * mu;
    float rs = rsqrtf(var + 1e-5f);
    float y0 = (v0 - mu) * rs * gw[tid] + bw[tid];
    float y1 = (v1 - mu) * rs * gw[tid + 256] + bw[tid + 256];
    X[base + tid] = y0;
    X[base + tid + 256] = y1;
    Xb[base + tid] = f2bf(y0);
    Xb[base + tid + 256] = f2bf(y1);
}

// ---------------- out = tanh(X @ dec_w^T + dec_b) * 10 ----------------
__global__ __launch_bounds__(256) void decoder_kernel(
    const float* __restrict__ X, const float* __restrict__ w,
    const float* __restrict__ bias, float* __restrict__ out)
{
    int tid = threadIdx.x;
    int lane = tid & 63;
    int row = blockIdx.x * 4 + (tid >> 6);
    float s = 0.f;
    size_t base = (size_t)row * DMODEL;
    #pragma unroll
    for (int i = 0; i < 8; i++) s = fmaf(X[base + lane + i * 64], w[lane + i * 64], s);
    #pragma unroll
    for (int off = 32; off > 0; off >>= 1) s += __shfl_down(s, off);
    if (lane == 0) out[row] = tanhf(s + bias[0]) * 10.0f;
}

extern "C" void kernel_launch(void* const* d_in, const int* in_sizes, int n_in,
                              void* d_out, int out_size, void* d_ws, size_t ws_size,
                              hipStream_t stream)
{
    const float* src   = (const float*)d_in[0];
    const float* emb_w = (const float*)d_in[1];
    const float* emb_b = (const float*)d_in[2];
    const float* in_w  = (const float*)d_in[3];
    const float* in_b  = (const float*)d_in[4];
    const float* out_w = (const float*)d_in[5];
    const float* out_b = (const float*)d_in[6];
    const float* ln1_g = (const float*)d_in[7];
    const float* ln1_b = (const float*)d_in[8];
    const float* ln2_g = (const float*)d_in[9];
    const float* ln2_b = (const float*)d_in[10];
    const float* ff1_w = (const float*)d_in[11];
    const float* ff1_b = (const float*)d_in[12];
    const float* ff2_w = (const float*)d_in[13];
    const float* ff2_b = (const float*)d_in[14];
    const float* dec_w = (const float*)d_in[15];
    const float* dec_b = (const float*)d_in[16];

    char* ws = (char*)d_ws;
    float*          X   = (float*)ws;                              // 16 MB
    unsigned short* Xb  = (unsigned short*)(ws + (16u << 20));     //  8 MB
    unsigned short* Pb  = (unsigned short*)(ws + (24u << 20));     //  8 MB
    unsigned short* Ob  = (unsigned short*)(ws + (32u << 20));     //  8 MB
    unsigned short* QKb = (unsigned short*)(ws + (40u << 20));     // 16 MB
    unsigned short* Vt  = (unsigned short*)(ws + (56u << 20));     //  8 MB
    unsigned short* Hb  = (unsigned short*)(ws + (40u << 20));     // 32 MB (overlaps QKb+Vt, disjoint in time)
    unsigned short* in_wb  = (unsigned short*)(ws + (72u << 20));
    unsigned short* out_wb = in_wb  + 3u * 1536 * 512;
    unsigned short* ff1_wb = out_wb + 3u * 512 * 512;
    unsigned short* ff2_wb = ff1_wb + 3u * 2048 * 512;
    float* outp = (float*)d_out;
    const int M = 4 * S_LEN;   // 8192

    conv_bf16<<<2304, 256, 0, stream>>>((const float4*)in_w,  (u16x4*)in_wb);
    conv_bf16<<<768,  256, 0, stream>>>((const float4*)out_w, (u16x4*)out_wb);
    conv_bf16<<<3072, 256, 0, stream>>>((const float4*)ff1_w, (u16x4*)ff1_wb);
    conv_bf16<<<3072, 256, 0, stream>>>((const float4*)ff2_w, (u16x4*)ff2_wb);

    embed_kernel<<<M, 256, 0, stream>>>(src, emb_w, emb_b, X, Xb);

    for (int l = 0; l < 3; l++) {
        gemm_bf16<3, 128><<<dim3(12, 64), 256, 0, stream>>>(
            Xb, 512, in_wb + (size_t)l * 1536 * 512, 512, in_b + l * 1536,
            QKb, 1024, Vt);
        flash_attn<<<dim3(512), 256, 0, stream>>>(QKb, Vt, Ob);
        gemm_bf16<1, 64><<<dim3(512), 256, 0, stream>>>(
            Ob, 512, out_wb + (size_t)l * 512 * 512, 512, out_b + l * 512,
            Pb, 512, nullptr);
        add_ln_kernel<<<M, 256, 0, stream>>>(X, Pb, ln1_g + l * 512, ln1_b + l * 512, Xb);
        gemm_bf16<2, 128><<<dim3(16, 64), 256, 0, stream>>>(
            Xb, 512, ff1_wb + (size_t)l * 2048 * 512, 512, ff1_b + l * 2048,
            Hb, 2048, nullptr);
        gemm_bf16<1, 64><<<dim3(512), 256, 0, stream>>>(
            Hb, 2048, ff2_wb + (size_t)l * 512 * 2048, 2048, ff2_b + l * 512,
            Pb, 512, nullptr);
        add_ln_kernel<<<M, 256, 0, stream>>>(X, Pb, ln2_g + l * 512, ln2_b + l * 512, Xb);
    }

    decoder_kernel<<<M / 4, 256, 0, stream>>>(X, dec_w, dec_b, outp);
}